// Round 2
// baseline (141.143 us; speedup 1.0000x reference)
//
#include <hip/hip_runtime.h>
#include <math.h>

#define NF 512        // feature count
#define NP 118        // params per feature
#define FT 32         // features per block tile
#define ROWS 8        // rows per thread
#define BLOCK_ROWS 64 // 256 threads / 32 features = 8 rowgroups * 8 rows
#define TBL_N 2048    // tanh table entries over [-8,8], +1 guard entry

__device__ __forceinline__ float fast_rcp(float x) {
    return __builtin_amdgcn_rcpf(x);
}

__device__ __forceinline__ float sigmoid_fast(float x) {
    return fast_rcp(1.0f + __expf(-x));
}

// Branchless LDS-table tanh: [-8,8] in 2048 bins, linear interp.
// med3 clamp -> guard entries give exact-ish saturation (err 2.3e-7).
__device__ __forceinline__ float tanh_lut(float x, const float* __restrict__ tbl) {
    float xi = fmaf(x, 128.0f, 1024.0f);
    xi = __builtin_amdgcn_fmed3f(xi, 0.0f, 2047.0f);
    float fl = floorf(xi);
    float fr = xi - fl;
    int   i  = (int)fl;
    float t0 = tbl[i];
    float t1 = tbl[i + 1];
    return fmaf(t1 - t0, fr, t0);
}

// Parameter class by flat index j in [0,118):
//  j<3 softplus(w L0), 3..5 copy(b), 6..8 tanh(s)
//  9..113: k=(j-9)%15 -> k<9 softplus(w), k<12 copy(b), else tanh(s)
//  114..116 softplus(w last), 117 copy(b last)
__device__ __forceinline__ float transform_one(float v, int j) {
    int cls;
    if (j < 3) cls = 0;
    else if (j < 6) cls = 1;
    else if (j < 9) cls = 2;
    else if (j < 114) { int k = (j - 9) % 15; cls = (k < 9) ? 0 : ((k < 12) ? 1 : 2); }
    else if (j < 117) cls = 0;
    else cls = 1;
    if (cls == 0) return fmaxf(v, 0.0f) + log1pf(expf(-fabsf(v)));  // stable softplus
    if (cls == 2) return tanhf(v);
    return v;
}

// Kernel 1: transform params once, store transposed t[j*NF + f].
__global__ void xform_kernel(const float* __restrict__ p, float* __restrict__ t) {
    int idx = blockIdx.x * 256 + threadIdx.x;
    if (idx >= NF * NP) return;
    int f = idx / NP;
    int j = idx - f * NP;
    t[j * NF + f] = transform_one(p[idx], j);
}

// Main kernel: thread = one feature column x 8 rows.
template <bool FUSE_XFORM>
__global__ __launch_bounds__(256)
void cdf_kernel(const float* __restrict__ x, const float* __restrict__ prm,
                float* __restrict__ out) {
    __shared__ float lds[NP * FT];     // [j][FT] param tiles, conflict-free lane reads
    __shared__ float tbl[TBL_N + 1];   // tanh LUT
    const int tid = threadIdx.x;
    const int fi  = tid & (FT - 1);
    const int rg  = tid >> 5;          // 8 rowgroups
    const int f0  = blockIdx.x * FT;
    const int b0  = blockIdx.y * BLOCK_ROWS + rg * ROWS;
    const int f   = f0 + fi;

    // stage params
    if constexpr (FUSE_XFORM) {
        for (int idx = tid; idx < FT * NP; idx += 256) {
            int fl = idx / NP;
            int j  = idx - fl * NP;
            lds[j * FT + fl] = transform_one(prm[(f0 + fl) * NP + j], j);
        }
    } else {
        for (int idx = tid; idx < NP * FT; idx += 256) {
            int j  = idx >> 5;
            int fl = idx & (FT - 1);
            lds[idx] = prm[j * NF + f0 + fl];
        }
    }
    // build tanh table (2049 tanhf amortized over 512 elements/block)
    for (int idx = tid; idx <= TBL_N; idx += 256)
        tbl[idx] = tanhf((float)(idx - 1024) * (1.0f / 128.0f));

    float xin[ROWS];
#pragma unroll
    for (int r = 0; r < ROWS; ++r)
        xin[r] = x[(b0 + r) * NF + f];

    __syncthreads();

    const float* Lp = lds + fi;
#define PRM(J) Lp[(J) * FT]

    float h0[ROWS], h1[ROWS], h2[ROWS];
    // layer 0: w (3,1), b, s
    {
        const float w0 = PRM(0), w1 = PRM(1), w2 = PRM(2);
        const float c0 = PRM(3), c1 = PRM(4), c2 = PRM(5);
        const float s0 = PRM(6), s1 = PRM(7), s2 = PRM(8);
#pragma unroll
        for (int r = 0; r < ROWS; ++r) {
            float a0 = fmaf(xin[r], w0, c0);
            float a1 = fmaf(xin[r], w1, c1);
            float a2 = fmaf(xin[r], w2, c2);
            h0[r] = fmaf(s0, tanh_lut(a0, tbl), a0);
            h1[r] = fmaf(s1, tanh_lut(a1, tbl), a1);
            h2[r] = fmaf(s2, tanh_lut(a2, tbl), a2);
        }
    }
    // middle layers 1..7: w (3,3) row-major, b, s
#pragma unroll
    for (int li = 1; li < 8; ++li) {
        const int base = 9 + 15 * (li - 1);
        const float w00 = PRM(base + 0), w01 = PRM(base + 1), w02 = PRM(base + 2);
        const float w10 = PRM(base + 3), w11 = PRM(base + 4), w12 = PRM(base + 5);
        const float w20 = PRM(base + 6), w21 = PRM(base + 7), w22 = PRM(base + 8);
        const float c0  = PRM(base + 9), c1  = PRM(base + 10), c2 = PRM(base + 11);
        const float s0  = PRM(base + 12), s1 = PRM(base + 13), s2 = PRM(base + 14);
#pragma unroll
        for (int r = 0; r < ROWS; ++r) {
            float a0 = fmaf(h0[r], w00, fmaf(h1[r], w01, fmaf(h2[r], w02, c0)));
            float a1 = fmaf(h0[r], w10, fmaf(h1[r], w11, fmaf(h2[r], w12, c1)));
            float a2 = fmaf(h0[r], w20, fmaf(h1[r], w21, fmaf(h2[r], w22, c2)));
            h0[r] = fmaf(s0, tanh_lut(a0, tbl), a0);
            h1[r] = fmaf(s1, tanh_lut(a1, tbl), a1);
            h2[r] = fmaf(s2, tanh_lut(a2, tbl), a2);
        }
    }
    // final layer: w (1,3), b, sigmoid
    {
        const float w0 = PRM(114), w1 = PRM(115), w2 = PRM(116), cb = PRM(117);
#pragma unroll
        for (int r = 0; r < ROWS; ++r) {
            float a = fmaf(h0[r], w0, fmaf(h1[r], w1, fmaf(h2[r], w2, cb)));
            out[(b0 + r) * NF + f] = sigmoid_fast(a);
        }
    }
#undef PRM
}

extern "C" void kernel_launch(void* const* d_in, const int* in_sizes, int n_in,
                              void* d_out, int out_size, void* d_ws, size_t ws_size,
                              hipStream_t stream) {
    const float* x = (const float*)d_in[0];       // (B, 512) f32
    const float* p = (const float*)d_in[1];       // (512, 118) f32
    float* out = (float*)d_out;                   // (B, 512) f32

    const int B = in_sizes[0] / NF;               // 32768
    dim3 grid(NF / FT, B / BLOCK_ROWS);           // (16, 512)
    dim3 block(256);

    if (ws_size >= (size_t)(NF * NP * sizeof(float))) {
        float* t = (float*)d_ws;
        xform_kernel<<<(NF * NP + 255) / 256, 256, 0, stream>>>(p, t);
        cdf_kernel<false><<<grid, block, 0, stream>>>(x, t, out);
    } else {
        cdf_kernel<true><<<grid, block, 0, stream>>>(x, p, out);
    }
}

// Round 3
// 111.356 us; speedup vs baseline: 1.2675x; 1.2675x over previous
//
#include <hip/hip_runtime.h>
#include <math.h>

#define NF 512        // feature count
#define NP 118        // raw params per feature
#define NPPAD 126     // padded: L0 at 0 (9+1 pad), middle li at 10+16*(li-1), final at 122
#define FT 32         // features per block tile
#define BLOCK_ROWS 64 // 256 threads / 32 features = 8 rowgroups * 8 rows
#define TBL_N 2048    // tanh slope/intercept bins over [-8,8]
#define WS_NEED ((size_t)(NPPAD * NF + 2 * TBL_N) * sizeof(float))

typedef float v2f __attribute__((ext_vector_type(2)));

__device__ __forceinline__ v2f pk_fma(v2f a, v2f b, v2f c) {
    return __builtin_elementwise_fma(a, b, c);
}
__device__ __forceinline__ v2f splat2(float v) { v2f r; r.x = v; r.y = v; return r; }

__device__ __forceinline__ float fast_rcp(float x) { return __builtin_amdgcn_rcpf(x); }

// pair tanh via slope/intercept LDS table: per scalar = fma(idx),med3,cvt,ds_read_b64,fma
__device__ __forceinline__ v2f tanh_lut2(v2f x, const v2f* __restrict__ tbl) {
    v2f xi = pk_fma(x, splat2(128.0f), splat2(1024.0f));
    float q0 = __builtin_amdgcn_fmed3f(xi.x, 0.0f, 2047.0f);
    float q1 = __builtin_amdgcn_fmed3f(xi.y, 0.0f, 2047.0f);
    v2f sc0 = tbl[(int)q0];   // trunc == floor (q >= 0)
    v2f sc1 = tbl[(int)q1];
    v2f r;
    r.x = fmaf(x.x, sc0.x, sc0.y);
    r.y = fmaf(x.y, sc1.x, sc1.y);
    return r;
}

// Raw-param class by flat index j in [0,118)
__device__ __forceinline__ float transform_one(float v, int j) {
    int cls;
    if (j < 3) cls = 0;
    else if (j < 6) cls = 1;
    else if (j < 9) cls = 2;
    else if (j < 114) { int k = (j - 9) % 15; cls = (k < 9) ? 0 : ((k < 12) ? 1 : 2); }
    else if (j < 117) cls = 0;
    else cls = 1;
    if (cls == 0) return fmaxf(v, 0.0f) + log1pf(expf(-fabsf(v)));  // stable softplus
    if (cls == 2) return tanhf(v);
    return v;
}

// padded index -> raw index; pad slots invalid
__device__ __forceinline__ bool map_padded(int jp, int* j) {
    if (jp < 9) { *j = jp; return true; }
    if (jp == 9) return false;
    if (jp < 122) {
        int k = (jp - 10) & 15, li = (jp - 10) >> 4;
        if (k == 15) return false;
        *j = 9 + 15 * li + k;
        return true;
    }
    *j = 114 + (jp - 122);
    return true;
}

__device__ __forceinline__ void tbl_entry(int bin, float* s, float* c) {
    if (bin == 0)              { *s = 0.0f; *c = -1.0f; }
    else if (bin == TBL_N - 1) { *s = 0.0f; *c =  1.0f; }
    else {
        float xl = (float)(bin - 1024) * (1.0f / 128.0f);
        float t0 = tanhf(xl), t1 = tanhf(xl + 1.0f / 128.0f);
        float sl = (t1 - t0) * 128.0f;
        *s = sl; *c = fmaf(-sl, xl, t0);
    }
}

// Kernel 1: transformed+padded params transposed t[jp*NF+f], then slope/intercept table.
__global__ void xform_kernel(const float* __restrict__ p, float* __restrict__ t) {
    int idx = blockIdx.x * 256 + threadIdx.x;
    if (idx < NPPAD * NF) {
        int jp = idx / NF, f = idx - jp * NF;
        int j; float v = 0.0f;
        if (map_padded(jp, &j)) v = transform_one(p[f * NP + j], j);
        t[idx] = v;
    } else if (idx < NPPAD * NF + TBL_N) {
        int bin = idx - NPPAD * NF;
        float s, c;
        tbl_entry(bin, &s, &c);
        t[NPPAD * NF + 2 * bin]     = s;
        t[NPPAD * NF + 2 * bin + 1] = c;
    }
}

template <bool FUSE_XFORM>
__global__ __launch_bounds__(256)
void cdf_kernel(const float* __restrict__ x, const float* __restrict__ prm,
                float* __restrict__ out) {
    __shared__ float ldsp[NPPAD * FT];   // pair-interleaved: [(jp>>1)][fi][2]
    __shared__ v2f   tblv[TBL_N];        // (slope, intercept)
    const int tid = threadIdx.x;
    const int fi  = tid & (FT - 1);
    const int rg  = tid >> 5;            // 8 rowgroups
    const int f0  = blockIdx.x * FT;
    const int b0  = blockIdx.y * BLOCK_ROWS + rg * 8;
    const int f   = f0 + fi;

    if constexpr (FUSE_XFORM) {
        for (int idx = tid; idx < NPPAD * FT; idx += 256) {
            int jp = idx >> 5, fl = idx & (FT - 1);
            int j; float v = 0.0f;
            if (map_padded(jp, &j)) v = transform_one(prm[(f0 + fl) * NP + j], j);
            ldsp[(jp >> 1) * (2 * FT) + fl * 2 + (jp & 1)] = v;
        }
        float* tf = (float*)tblv;
        for (int bin = tid; bin < TBL_N; bin += 256) {
            float s, c; tbl_entry(bin, &s, &c);
            tf[2 * bin] = s; tf[2 * bin + 1] = c;
        }
    } else {
        for (int idx = tid; idx < NPPAD * FT; idx += 256) {
            int jp = idx >> 5, fl = idx & (FT - 1);
            ldsp[(jp >> 1) * (2 * FT) + fl * 2 + (jp & 1)] = prm[jp * NF + f0 + fl];
        }
        float* tf = (float*)tblv;
        const float* tw = prm + NPPAD * NF;
        for (int idx = tid; idx < 2 * TBL_N; idx += 256)
            tf[idx] = tw[idx];
    }

    v2f xin[4];
#pragma unroll
    for (int r = 0; r < 4; ++r) {
        xin[r].x = x[(b0 + 2 * r)     * NF + f];
        xin[r].y = x[(b0 + 2 * r + 1) * NF + f];
    }

    __syncthreads();

    const float* Pp = ldsp + fi * 2;
    // JP even: pair {p[JP], p[JP+1]} at offset JP*FT floats (8B aligned)
#define PRMV(JP) (*reinterpret_cast<const v2f*>(Pp + (JP) * FT))

    v2f h0[4], h1[4], h2[4];
    // ---- layer 0 (padded base 0): w0..2, b0..2, s0..2 ----
    {
        v2f p01 = PRMV(0), p23 = PRMV(2), p45 = PRMV(4), p67 = PRMV(6), p8p = PRMV(8);
        const float w0 = p01.x, w1 = p01.y, w2 = p23.x;
        const float c0 = p23.y, c1 = p45.x, c2 = p45.y;
        const float s0 = p67.x, s1 = p67.y, s2 = p8p.x;
#pragma unroll
        for (int r = 0; r < 4; ++r) {
            v2f a0 = pk_fma(xin[r], splat2(w0), splat2(c0));
            v2f a1 = pk_fma(xin[r], splat2(w1), splat2(c1));
            v2f a2 = pk_fma(xin[r], splat2(w2), splat2(c2));
            h0[r] = pk_fma(splat2(s0), tanh_lut2(a0, tblv), a0);
            h1[r] = pk_fma(splat2(s1), tanh_lut2(a1, tblv), a1);
            h2[r] = pk_fma(splat2(s2), tanh_lut2(a2, tblv), a2);
        }
    }
    // ---- middle layers 1..7 (padded base 10+16*(li-1)) ----
#pragma unroll
    for (int li = 1; li < 8; ++li) {
        const int bp = 10 + 16 * (li - 1);
        v2f q0 = PRMV(bp + 0), q1 = PRMV(bp + 2), q2 = PRMV(bp + 4), q3 = PRMV(bp + 6);
        v2f q4 = PRMV(bp + 8), q5 = PRMV(bp + 10), q6 = PRMV(bp + 12), q7 = PRMV(bp + 14);
        const float w00 = q0.x, w01 = q0.y, w02 = q1.x;
        const float w10 = q1.y, w11 = q2.x, w12 = q2.y;
        const float w20 = q3.x, w21 = q3.y, w22 = q4.x;
        const float c0  = q4.y, c1  = q5.x, c2  = q5.y;
        const float s0  = q6.x, s1  = q6.y, s2  = q7.x;
#pragma unroll
        for (int r = 0; r < 4; ++r) {
            v2f a0 = pk_fma(h0[r], splat2(w00), pk_fma(h1[r], splat2(w01), pk_fma(h2[r], splat2(w02), splat2(c0))));
            v2f a1 = pk_fma(h0[r], splat2(w10), pk_fma(h1[r], splat2(w11), pk_fma(h2[r], splat2(w12), splat2(c1))));
            v2f a2 = pk_fma(h0[r], splat2(w20), pk_fma(h1[r], splat2(w21), pk_fma(h2[r], splat2(w22), splat2(c2))));
            h0[r] = pk_fma(splat2(s0), tanh_lut2(a0, tblv), a0);
            h1[r] = pk_fma(splat2(s1), tanh_lut2(a1, tblv), a1);
            h2[r] = pk_fma(splat2(s2), tanh_lut2(a2, tblv), a2);
        }
    }
    // ---- final layer (padded base 122): w0..2, b; sigmoid ----
    {
        v2f q0 = PRMV(122), q1 = PRMV(124);
        const float w0 = q0.x, w1 = q0.y, w2 = q1.x, cb = q1.y;
#pragma unroll
        for (int r = 0; r < 4; ++r) {
            v2f a = pk_fma(h0[r], splat2(w0),
                    pk_fma(h1[r], splat2(w1),
                    pk_fma(h2[r], splat2(w2), splat2(cb))));
            out[(b0 + 2 * r)     * NF + f] = fast_rcp(1.0f + __expf(-a.x));
            out[(b0 + 2 * r + 1) * NF + f] = fast_rcp(1.0f + __expf(-a.y));
        }
    }
#undef PRMV
}

extern "C" void kernel_launch(void* const* d_in, const int* in_sizes, int n_in,
                              void* d_out, int out_size, void* d_ws, size_t ws_size,
                              hipStream_t stream) {
    const float* x = (const float*)d_in[0];       // (B, 512) f32
    const float* p = (const float*)d_in[1];       // (512, 118) f32
    float* out = (float*)d_out;                   // (B, 512) f32

    const int B = in_sizes[0] / NF;               // 32768
    dim3 grid(NF / FT, B / BLOCK_ROWS);           // (16, 512)
    dim3 block(256);

    if (ws_size >= WS_NEED) {
        float* t = (float*)d_ws;
        int total = NPPAD * NF + TBL_N;
        xform_kernel<<<(total + 255) / 256, 256, 0, stream>>>(p, t);
        cdf_kernel<false><<<grid, block, 0, stream>>>(x, t, out);
    } else {
        cdf_kernel<true><<<grid, block, 0, stream>>>(x, p, out);
    }
}

// Round 4
// 104.897 us; speedup vs baseline: 1.3455x; 1.0616x over previous
//
#include <hip/hip_runtime.h>
#include <math.h>

#define NF 512        // feature count
#define NP 118        // raw params per feature
#define NPPAD 126     // padded: L0 at 0 (9+1 pad), middle li at 10+16*(li-1), final at 122
#define FT 16         // features per block tile
#define ROWS 8        // rows per thread (4 row-pairs)
#define BLOCK_ROWS 128 // (256/FT) rowgroups * ROWS
#define TBL_N 2048    // tanh secant bins, centered, over ~[-8,8]
#define WS_NEED ((size_t)(NPPAD * NF + 2 * TBL_N) * sizeof(float))

typedef float v2f __attribute__((ext_vector_type(2)));

// ---- explicit VOP3P packed fp32 FMA with op_sel broadcasts ----
// Naming f_XY: src1 uses half X, src2 uses half Y; P = normal pair.
// op_sel:[s0,s1,s2] picks source half for LO result; op_sel_hi for HI result.
__device__ __forceinline__ v2f f_PP(v2f a, v2f b, v2f c) {
    v2f d; asm("v_pk_fma_f32 %0, %1, %2, %3" : "=v"(d) : "v"(a), "v"(b), "v"(c)); return d;
}
__device__ __forceinline__ v2f f_LP(v2f a, v2f b, v2f c) {  // b broadcast lo
    v2f d; asm("v_pk_fma_f32 %0, %1, %2, %3 op_sel_hi:[1,0,1]" : "=v"(d) : "v"(a), "v"(b), "v"(c)); return d;
}
__device__ __forceinline__ v2f f_HP(v2f a, v2f b, v2f c) {  // b broadcast hi
    v2f d; asm("v_pk_fma_f32 %0, %1, %2, %3 op_sel:[0,1,0] op_sel_hi:[1,1,1]" : "=v"(d) : "v"(a), "v"(b), "v"(c)); return d;
}
__device__ __forceinline__ v2f f_LH(v2f a, v2f b, v2f c) {  // b lo, c hi
    v2f d; asm("v_pk_fma_f32 %0, %1, %2, %3 op_sel:[0,0,1] op_sel_hi:[1,0,1]" : "=v"(d) : "v"(a), "v"(b), "v"(c)); return d;
}
__device__ __forceinline__ v2f f_HL(v2f a, v2f b, v2f c) {  // b hi, c lo
    v2f d; asm("v_pk_fma_f32 %0, %1, %2, %3 op_sel:[0,1,0] op_sel_hi:[1,1,0]" : "=v"(d) : "v"(a), "v"(b), "v"(c)); return d;
}

// secant-line tanh over centered bins: idx = trunc(clamp(x*128 + 1024.5))
__device__ __forceinline__ v2f tanh_pair(v2f x, const v2f* __restrict__ tbl,
                                         v2f K128, v2f K1024) {
    v2f xi = f_PP(x, K128, K1024);
    float q0 = __builtin_amdgcn_fmed3f(xi.x, 0.0f, 2047.0f);
    float q1 = __builtin_amdgcn_fmed3f(xi.y, 0.0f, 2047.0f);
    v2f sc0 = tbl[(int)q0];
    v2f sc1 = tbl[(int)q1];
    v2f r;
    r.x = fmaf(x.x, sc0.x, sc0.y);
    r.y = fmaf(x.y, sc1.x, sc1.y);
    return r;
}

// ---- parameter transform (host-side params -> softplus/tanh/copy) ----
__device__ __forceinline__ float transform_one(float v, int j) {
    int cls;
    if (j < 3) cls = 0;
    else if (j < 6) cls = 1;
    else if (j < 9) cls = 2;
    else if (j < 114) { int k = (j - 9) % 15; cls = (k < 9) ? 0 : ((k < 12) ? 1 : 2); }
    else if (j < 117) cls = 0;
    else cls = 1;
    if (cls == 0) return fmaxf(v, 0.0f) + log1pf(expf(-fabsf(v)));  // stable softplus
    if (cls == 2) return tanhf(v);
    return v;
}

__device__ __forceinline__ bool map_padded(int jp, int* j) {
    if (jp < 9) { *j = jp; return true; }
    if (jp == 9) return false;
    if (jp < 122) {
        int k = (jp - 10) & 15, li = (jp - 10) >> 4;
        if (k == 15) return false;
        *j = 9 + 15 * li + k;
        return true;
    }
    *j = 114 + (jp - 122);
    return true;
}

// final layer pre-scaled by 0.5 so sigmoid(a) = 0.5 + 0.5*tanh(a_half)
__device__ __forceinline__ float transform_padded(const float* __restrict__ prow, int jp) {
    int j;
    if (!map_padded(jp, &j)) return 0.0f;
    float v = transform_one(prow[j], j);
    if (jp >= 122) v *= 0.5f;
    return v;
}

// secant over centered bin b: x in [(b-1024.5)/128, (b-1023.5)/128)
__device__ __forceinline__ void tbl_entry(int b, float* s, float* c) {
    float xl = (float)b * (1.0f / 128.0f) - (1024.5f / 128.0f);
    float xr = xl + (1.0f / 128.0f);
    float t0 = tanhf(xl), t1 = tanhf(xr);
    float sl = (t1 - t0) * 128.0f;
    *s = sl;
    *c = fmaf(-sl, xl, t0);
}

// Kernel 1: padded+transformed params transposed t[jp*NF+f], then (s,c) table.
__global__ void xform_kernel(const float* __restrict__ p, float* __restrict__ t) {
    int idx = blockIdx.x * 256 + threadIdx.x;
    if (idx < NPPAD * NF) {
        int jp = idx / NF, f = idx - jp * NF;
        t[idx] = transform_padded(p + f * NP, jp);
    } else if (idx < NPPAD * NF + TBL_N) {
        int bin = idx - NPPAD * NF;
        float s, c;
        tbl_entry(bin, &s, &c);
        t[NPPAD * NF + 2 * bin]     = s;
        t[NPPAD * NF + 2 * bin + 1] = c;
    }
}

template <bool FUSE_XFORM>
__global__ __launch_bounds__(256, 6)
void cdf_kernel(const float* __restrict__ x, const float* __restrict__ prm,
                float* __restrict__ out) {
    __shared__ float ldsp[NPPAD * FT];   // pair-interleaved: [(jp>>1)][fi][2]
    __shared__ v2f   tblv[TBL_N];        // (slope, intercept)
    const int tid = threadIdx.x;
    const int fi  = tid & (FT - 1);
    const int rg  = tid >> 4;            // 16 rowgroups
    const int f0  = blockIdx.x * FT;
    const int b0  = blockIdx.y * BLOCK_ROWS + rg * ROWS;
    const int f   = f0 + fi;

    if constexpr (FUSE_XFORM) {
        for (int idx = tid; idx < NPPAD * FT; idx += 256) {
            int jp = idx >> 4, fl = idx & (FT - 1);
            ldsp[(jp >> 1) * (2 * FT) + fl * 2 + (jp & 1)] =
                transform_padded(prm + (f0 + fl) * NP, jp);
        }
        float* tf = (float*)tblv;
        for (int bin = tid; bin < TBL_N; bin += 256) {
            float s, c; tbl_entry(bin, &s, &c);
            tf[2 * bin] = s; tf[2 * bin + 1] = c;
        }
    } else {
        for (int idx = tid; idx < NPPAD * FT; idx += 256) {
            int jp = idx >> 4, fl = idx & (FT - 1);
            ldsp[(jp >> 1) * (2 * FT) + fl * 2 + (jp & 1)] = prm[jp * NF + f0 + fl];
        }
        float* tf = (float*)tblv;
        const float* tw = prm + NPPAD * NF;
        for (int idx = tid; idx < 2 * TBL_N; idx += 256)
            tf[idx] = tw[idx];
    }

    v2f xin[4];
#pragma unroll
    for (int r = 0; r < 4; ++r) {
        xin[r].x = x[(b0 + 2 * r)     * NF + f];
        xin[r].y = x[(b0 + 2 * r + 1) * NF + f];
    }

    __syncthreads();

    const v2f K128  = {128.0f, 128.0f};
    const v2f K1024 = {1024.5f, 1024.5f};
    const v2f Khalf = {0.5f, 0.5f};

    const float* Pp = ldsp + fi * 2;
#define PRMV(JP) (*reinterpret_cast<const v2f*>(Pp + (JP) * FT))

    v2f h0[4], h1[4], h2[4];
    // ---- layer 0: pairs {w0,w1},{w2,c0},{c1,c2},{s0,s1},{s2,pad} ----
    {
        v2f q0 = PRMV(0), q1 = PRMV(2), q2 = PRMV(4), q3 = PRMV(6), q4 = PRMV(8);
#pragma unroll
        for (int r = 0; r < 4; ++r) {
            v2f a0 = f_LH(xin[r], q0, q1);   // w0*x + c0
            v2f a1 = f_HL(xin[r], q0, q2);   // w1*x + c1
            v2f a2 = f_LH(xin[r], q1, q2);   // w2*x + c2
            v2f T0 = tanh_pair(a0, tblv, K128, K1024);
            v2f T1 = tanh_pair(a1, tblv, K128, K1024);
            v2f T2 = tanh_pair(a2, tblv, K128, K1024);
            h0[r] = f_LP(T0, q3, a0);        // a0 + s0*T0
            h1[r] = f_HP(T1, q3, a1);        // a1 + s1*T1
            h2[r] = f_LP(T2, q4, a2);        // a2 + s2*T2
        }
    }
    // ---- middle layers 1..7: pairs {w00,w01},{w02,w10},{w11,w12},{w20,w21},
    //                                 {w22,c0},{c1,c2},{s0,s1},{s2,pad} ----
#pragma unroll
    for (int li = 1; li < 8; ++li) {
        const int bp = 10 + 16 * (li - 1);
        v2f q0 = PRMV(bp + 0), q1 = PRMV(bp + 2), q2 = PRMV(bp + 4), q3 = PRMV(bp + 6);
        v2f q4 = PRMV(bp + 8), q5 = PRMV(bp + 10), q6 = PRMV(bp + 12), q7 = PRMV(bp + 14);
#pragma unroll
        for (int r = 0; r < 4; ++r) {
            v2f t0 = f_LH(h0[r], q0, q4);    // w00*h0 + c0
            t0     = f_HP(h1[r], q0, t0);    // + w01*h1
            v2f a0 = f_LP(h2[r], q1, t0);    // + w02*h2
            v2f t1 = f_HL(h0[r], q1, q5);    // w10*h0 + c1
            t1     = f_LP(h1[r], q2, t1);    // + w11*h1
            v2f a1 = f_HP(h2[r], q2, t1);    // + w12*h2
            v2f t2 = f_LH(h0[r], q3, q5);    // w20*h0 + c2
            t2     = f_HP(h1[r], q3, t2);    // + w21*h1
            v2f a2 = f_LP(h2[r], q4, t2);    // + w22*h2
            v2f T0 = tanh_pair(a0, tblv, K128, K1024);
            v2f T1 = tanh_pair(a1, tblv, K128, K1024);
            v2f T2 = tanh_pair(a2, tblv, K128, K1024);
            h0[r] = f_LP(T0, q6, a0);
            h1[r] = f_HP(T1, q6, a1);
            h2[r] = f_LP(T2, q7, a2);
        }
    }
    // ---- final layer (weights pre-scaled by 0.5): sigmoid = 0.5 + 0.5*tanh ----
    {
        v2f q8 = PRMV(122), q9 = PRMV(124);  // {w0h,w1h},{w2h,cbh}
#pragma unroll
        for (int r = 0; r < 4; ++r) {
            v2f a = f_LH(h0[r], q8, q9);
            a     = f_HP(h1[r], q8, a);
            a     = f_LP(h2[r], q9, a);
            v2f T = tanh_pair(a, tblv, K128, K1024);
            v2f o = f_PP(T, Khalf, Khalf);
            out[(b0 + 2 * r)     * NF + f] = o.x;
            out[(b0 + 2 * r + 1) * NF + f] = o.y;
        }
    }
#undef PRMV
}

extern "C" void kernel_launch(void* const* d_in, const int* in_sizes, int n_in,
                              void* d_out, int out_size, void* d_ws, size_t ws_size,
                              hipStream_t stream) {
    const float* x = (const float*)d_in[0];       // (B, 512) f32
    const float* p = (const float*)d_in[1];       // (512, 118) f32
    float* out = (float*)d_out;                   // (B, 512) f32

    const int B = in_sizes[0] / NF;               // 32768
    dim3 grid(NF / FT, B / BLOCK_ROWS);           // (32, 256)
    dim3 block(256);

    if (ws_size >= WS_NEED) {
        float* t = (float*)d_ws;
        int total = NPPAD * NF + TBL_N;
        xform_kernel<<<(total + 255) / 256, 256, 0, stream>>>(p, t);
        cdf_kernel<false><<<grid, block, 0, stream>>>(x, t, out);
    } else {
        cdf_kernel<true><<<grid, block, 0, stream>>>(x, p, out);
    }
}